// Round 6
// baseline (326.646 us; speedup 1.0000x reference)
//
#include <hip/hip_runtime.h>
#include <hip/hip_bf16.h>

#define S_LEN 2048
#define NF 1024
#define NH 16
#define HD 64
#define NB 2
#define M_TOT 4096  // NB*S_LEN

typedef __bf16 bf16x8 __attribute__((ext_vector_type(8)));
typedef float f32x4 __attribute__((ext_vector_type(4)));
typedef unsigned short u16;

__device__ __forceinline__ u16 f2bf(float f) {
  union { float f; unsigned u; } v; v.f = f;
  unsigned r = v.u + 0x7FFFu + ((v.u >> 16) & 1u);
  return (u16)(r >> 16);
}

__device__ __forceinline__ unsigned pk2bf(float a, float b) {
  __hip_bfloat162 t = __float22bfloat162_rn(make_float2(a, b));
  union { __hip_bfloat162 h; unsigned u; } u; u.h = t; return u.u;
}

__device__ __forceinline__ f32x4 mfma16(bf16x8 a, bf16x8 b, f32x4 c) {
  return __builtin_amdgcn_mfma_f32_16x16x32_bf16(a, b, c, 0, 0, 0);
}

// async global->LDS 16B: lds dest is wave-uniform base + lane*16
__device__ __forceinline__ void gll16(const u16* g, u16* l) {
  __builtin_amdgcn_global_load_lds(
      (const __attribute__((address_space(1))) unsigned int*)g,
      (__attribute__((address_space(3))) unsigned int*)l, 16, 0, 0);
}

// XOR-swizzled LDS addressing: 64-u16 rows (128 B = 8 chunks of 16 B),
// chunk' = chunk ^ (row&7) -> conflict-free b128 for staging writes and
// fragment reads (verified: R3 dropped SQ_LDS_BANK_CONFLICT 5.4M->1.1M).
__device__ __forceinline__ u16* swz(u16* base, int row, int chunk) {
  return (u16*)((char*)base + row * 128 + ((chunk ^ (row & 7)) * 16));
}
__device__ __forceinline__ const u16* swz(const u16* base, int row, int chunk) {
  return (const u16*)((const char*)base + row * 128 + ((chunk ^ (row & 7)) * 16));
}

// ---- cast fp32 -> bf16, 4 elems/thread ----
__global__ void __launch_bounds__(256) cast_kernel(const float* __restrict__ in,
                                                   u16* __restrict__ out) {
  int i = (blockIdx.x * 256 + threadIdx.x) * 4;
  float4 v = *(const float4*)(in + i);
  ushort4 o;
  o.x = f2bf(v.x); o.y = f2bf(v.y); o.z = f2bf(v.z); o.w = f2bf(v.w);
  *(ushort4*)(out + i) = o;
}

// ---- rope table: tab[(b*S+s)*32 + p] = (sin, cos) ----
__global__ void __launch_bounds__(256) rope_table_kernel(const int* __restrict__ positions,
                                                         float2* __restrict__ tab) {
  int idx = blockIdx.x * 256 + threadIdx.x;  // < NB*S_LEN*32
  int p = idx & 31;
  int bs = idx >> 5;
  float pos = (float)positions[bs];
  float ang = pos / __powf(10000.0f, (float)p * (1.0f / 32.0f));
  float sn, cs;
  sincosf(ang, &sn, &cs);
  tab[idx] = make_float2(sn, cs);
}

// ---- weight transpose + cast (all 4 weights in one dispatch): Wt[n][k] = W[k][n] ----
__global__ void __launch_bounds__(256) wtrans_kernel(
    const float* __restrict__ W0, const float* __restrict__ W1,
    const float* __restrict__ W2, const float* __restrict__ W3,
    u16* __restrict__ T0, u16* __restrict__ T1,
    u16* __restrict__ T2, u16* __restrict__ T3) {
  const float* W = (blockIdx.z == 0) ? W0 : (blockIdx.z == 1) ? W1 : (blockIdx.z == 2) ? W2 : W3;
  u16* Wt = (blockIdx.z == 0) ? T0 : (blockIdx.z == 1) ? T1 : (blockIdx.z == 2) ? T2 : T3;
  __shared__ float t[32][33];
  int n0 = blockIdx.x * 32, k0 = blockIdx.y * 32;
  int tx = threadIdx.x, ty0 = threadIdx.y;
#pragma unroll
  for (int i = 0; i < 4; i++) {
    int ty = ty0 + i * 8;
    t[ty][tx] = W[(size_t)(k0 + ty) * NF + n0 + tx];
  }
  __syncthreads();
#pragma unroll
  for (int i = 0; i < 4; i++) {
    int ty = ty0 + i * 8;
    Wt[(size_t)(n0 + ty) * NF + k0 + tx] = f2bf(t[tx][ty]);
  }
}

// 128x128 tile bf16 GEMM core: C = A[M,K] * Bt[N,K]^T, K=1024.
// Unpadded [128][32] u16 tiles staged via global_load_lds (m97 pattern).
__device__ __forceinline__ void mm_core(const u16* __restrict__ A, const u16* __restrict__ Bt,
                                        int m0, int n0, u16* As, u16* Bs, f32x4 acc[4][4]) {
  const int tid = threadIdx.x;
  const int lane = tid & 63, w = tid >> 6;
  const int l15 = lane & 15, quad = lane >> 4;
  const int wr = w >> 1, wc = w & 1;
#pragma unroll
  for (int i = 0; i < 4; i++)
#pragma unroll
    for (int j = 0; j < 4; j++) {
      f32x4 z = {0.f, 0.f, 0.f, 0.f};
      acc[i][j] = z;
    }
  for (int k0 = 0; k0 < NF; k0 += 32) {
    __syncthreads();  // prior tile's reads done before overwrite
#pragma unroll
    for (int i = 0; i < 2; i++) {
      int ci = (w * 2 + i) * 64 + lane;  // chunk index in [0,512)
      int row = ci >> 2, c = ci & 3;
      gll16(&A[(size_t)(m0 + row) * NF + k0 + c * 8], &As[(w * 2 + i) * 512]);
      gll16(&Bt[(size_t)(n0 + row) * NF + k0 + c * 8], &Bs[(w * 2 + i) * 512]);
    }
    __syncthreads();  // drains vmcnt: tiles staged
    bf16x8 af[4], bfr[4];
#pragma unroll
    for (int i = 0; i < 4; i++)
      af[i] = *(const bf16x8*)&As[(wr * 64 + i * 16 + l15) * 32 + quad * 8];
#pragma unroll
    for (int j = 0; j < 4; j++)
      bfr[j] = *(const bf16x8*)&Bs[(wc * 64 + j * 16 + l15) * 32 + quad * 8];
#pragma unroll
    for (int i = 0; i < 4; i++)
#pragma unroll
      for (int j = 0; j < 4; j++)
        acc[i][j] = mfma16(af[i], bfr[j], acc[i][j]);
  }
}

#define QSCL 0.18033688f  // 0.125 * log2(e): folds score scale + exp->exp2 into q

// ---- fused QKV projection: z=0 -> q (rope, scaled), z=1 -> k (rope), z=2 -> v (transposed) ----
__global__ void __launch_bounds__(256) gemm_qkv_kernel(
    const u16* __restrict__ xb,
    const u16* __restrict__ wtq, const u16* __restrict__ wtk, const u16* __restrict__ wtv,
    const float* __restrict__ bq, const float* __restrict__ bk, const float* __restrict__ bv,
    const float2* __restrict__ rtab,
    u16* __restrict__ qo, u16* __restrict__ ko, u16* __restrict__ vto) {
  __shared__ u16 As[128 * 32], Bs[128 * 32];
  const int z = blockIdx.z;
  const u16* Wt = (z == 0) ? wtq : (z == 1) ? wtk : wtv;
  const float* bias = (z == 0) ? bq : (z == 1) ? bk : bv;
  const int m0 = blockIdx.y * 128, n0 = blockIdx.x * 128;
  f32x4 acc[4][4];
  mm_core(xb, Wt, m0, n0, As, Bs, acc);
  const int tid = threadIdx.x;
  const int lane = tid & 63, w = tid >> 6;
  const int l15 = lane & 15, quad = lane >> 4;
  const int wr = w >> 1, wc = w & 1;
  if (z < 2) {
    u16* out = (z == 0) ? qo : ko;
    const float oscl = (z == 0) ? QSCL : 1.0f;
#pragma unroll
    for (int i = 0; i < 4; i++) {
#pragma unroll
      for (int r = 0; r < 4; r++) {
        int gm = m0 + wr * 64 + i * 16 + quad * 4 + r;  // = b*S + s
        int b = gm >> 11, s = gm & 2047;
#pragma unroll
        for (int j = 0; j < 2; j++) {
          int col1 = n0 + wc * 64 + j * 16 + l15;
          int p = j * 16 + l15;
          float2 sc = rtab[gm * 32 + p];
          float x1 = acc[i][j][r] + bias[col1];
          float x2 = acc[i][j + 2][r] + bias[col1 + 32];
          float o1 = (x1 * sc.y - x2 * sc.x) * oscl;
          float o2 = (x2 * sc.y + x1 * sc.x) * oscl;
          int h = col1 >> 6;
          size_t base = ((size_t)((b * NH + h) * S_LEN + s)) * HD;
          out[base + p] = f2bf(o1);
          out[base + p + 32] = f2bf(o2);
        }
      }
    }
  } else {
    // v: write transposed [bh][d][s]
#pragma unroll
    for (int i = 0; i < 4; i++) {
      int gm0 = m0 + wr * 64 + i * 16 + quad * 4;
      int b = gm0 >> 11, s0 = gm0 & 2047;
#pragma unroll
      for (int j = 0; j < 4; j++) {
        int col = n0 + wc * 64 + j * 16 + l15;
        int h = col >> 6, d = col & 63;
        float bb = bias[col];
        ushort4 pk;
        pk.x = f2bf(acc[i][j][0] + bb);
        pk.y = f2bf(acc[i][j][1] + bb);
        pk.z = f2bf(acc[i][j][2] + bb);
        pk.w = f2bf(acc[i][j][3] + bb);
        *(ushort4*)&vto[((size_t)((b * NH + h) * HD + d)) * S_LEN + s0] = pk;
      }
    }
  }
}

// ---- output projection: fp32 out ----
__global__ void __launch_bounds__(256) gemm_o_kernel(const u16* __restrict__ ab,
                                                     const u16* __restrict__ wto,
                                                     const float* __restrict__ bo,
                                                     float* __restrict__ out) {
  __shared__ u16 As[128 * 32], Bs[128 * 32];
  const int m0 = blockIdx.y * 128, n0 = blockIdx.x * 128;
  f32x4 acc[4][4];
  mm_core(ab, wto, m0, n0, As, Bs, acc);
  const int tid = threadIdx.x;
  const int lane = tid & 63, w = tid >> 6;
  const int l15 = lane & 15, quad = lane >> 4;
  const int wr = w >> 1, wc = w & 1;
#pragma unroll
  for (int i = 0; i < 4; i++) {
#pragma unroll
    for (int j = 0; j < 4; j++) {
      int col = n0 + wc * 64 + j * 16 + l15;
      float bb = bo[col];
#pragma unroll
      for (int r = 0; r < 4; r++) {
        int gm = m0 + wr * 64 + i * 16 + quad * 4 + r;
        out[(size_t)gm * NF + col] = acc[i][j][r] + bb;
      }
    }
  }
}

// ---- flash attention, causal, S^T formulation, BK=64 ----
// R4's proven inner loop (VGPR=64: single-buffered K/V, 4-uint4 register
// prefetch, ones-B MFMA row-sum, shuffle-free epilogue) on R3's block-
// parallel grid (512 blocks, complementary qt mapping) — no split-K, no
// device fences. 32 KB LDS -> 5 blocks/CU for latency hiding.
__global__ void __launch_bounds__(256, 5) attn_kernel(
    const u16* __restrict__ qb, const u16* __restrict__ kb,
    const u16* __restrict__ vtb, u16* __restrict__ ob) {
  __shared__ u16 ks[64 * 64];     // [s' (64)][d (64)] swizzled
  __shared__ u16 vs[64 * 64];     // [d (64)][s' (64)] swizzled
  __shared__ u16 ps[4][32 * 64];  // per-wave P relayout
  const int bx = blockIdx.x;
  // complementary mapping: blocks i and i+256 have qt summing to 15
  const int qt = (bx < 256) ? (15 - (bx >> 5)) : ((bx - 256) >> 5);
  const int bh = bx & 31;
  const int tid = threadIdx.x;
  const int lane = tid & 63, w = tid >> 6, l15 = lane & 15, quad = lane >> 4;
  const int bb = bh >> 4, h = bh & 15;
  const size_t kvbase = (size_t)bh * S_LEN;
  const size_t vbase = (size_t)bh * HD;
  const int Q0 = qt * 128;
  const int nit = 2 * (qt + 1);
  const int r0 = tid >> 3, c0 = tid & 7;  // staging: 64 rows x 8 chunks
  const int r1 = r0 + 32;

  bf16x8 ones;
#pragma unroll
  for (int i = 0; i < 8; i++) ones[i] = (__bf16)1.0f;

  // Q fragments (B-operand: col=l15=q, k=quad*8+j=d)
  bf16x8 qf[2][2];
#pragma unroll
  for (int c = 0; c < 2; c++) {
    const u16* qrow = &qb[(kvbase + Q0 + w * 32 + c * 16 + l15) * HD];
#pragma unroll
    for (int hh = 0; hh < 2; hh++)
      qf[c][hh] = *(const bf16x8*)&qrow[hh * 32 + quad * 8];
  }

  float mrun[2] = {-1e30f, -1e30f};
  f32x4 Oa[2][4], lacc[2];
#pragma unroll
  for (int g = 0; g < 2; g++) {
    f32x4 z = {0.f, 0.f, 0.f, 0.f};
    lacc[g] = z;
#pragma unroll
    for (int t = 0; t < 4; t++) Oa[g][t] = z;
  }

  // stage first tile
  *(uint4*)swz(ks, r0, c0) = *(const uint4*)&kb[(kvbase + r0) * HD + c0 * 8];
  *(uint4*)swz(ks, r1, c0) = *(const uint4*)&kb[(kvbase + r1) * HD + c0 * 8];
  *(uint4*)swz(vs, r0, c0) = *(const uint4*)&vtb[(vbase + r0) * S_LEN + c0 * 8];
  *(uint4*)swz(vs, r1, c0) = *(const uint4*)&vtb[(vbase + r1) * S_LEN + c0 * 8];
  __syncthreads();

  for (int it = 0; it < nit; ++it) {
    const int k0 = it * 64;
    const bool pf = (it + 1 < nit);
    uint4 pk0, pk1, pv0, pv1;
    if (pf) {  // register prefetch of next K/V tile (overlaps compute)
      int k1 = k0 + 64;
      pk0 = *(const uint4*)&kb[(kvbase + k1 + r0) * HD + c0 * 8];
      pk1 = *(const uint4*)&kb[(kvbase + k1 + r1) * HD + c0 * 8];
      pv0 = *(const uint4*)&vtb[(vbase + r0) * S_LEN + k1 + c0 * 8];
      pv1 = *(const uint4*)&vtb[(vbase + r1) * S_LEN + k1 + c0 * 8];
    }
    // S^T = K.Q^T : per wave 64s x 32q
    f32x4 sf[2][4];
#pragma unroll
    for (int t = 0; t < 4; t++) {
      bf16x8 ak0 = *(const bf16x8*)swz(ks, t * 16 + l15, quad);
      bf16x8 ak1 = *(const bf16x8*)swz(ks, t * 16 + l15, 4 + quad);
#pragma unroll
      for (int c = 0; c < 2; c++) {
        f32x4 z = {0.f, 0.f, 0.f, 0.f};
        z = mfma16(ak0, qf[c][0], z);
        z = mfma16(ak1, qf[c][1], z);
        sf[c][t] = z;
      }
    }
    if (it >= 2 * qt) {  // causal mask (diagonal tiles only)
#pragma unroll
      for (int c = 0; c < 2; c++) {
        int qg = Q0 + w * 32 + c * 16 + l15;
#pragma unroll
        for (int t = 0; t < 4; t++)
#pragma unroll
          for (int rr = 0; rr < 4; rr++)
            if (k0 + t * 16 + quad * 4 + rr > qg) sf[c][t][rr] = -1e30f;
      }
    }
    // online softmax per q: in-lane max + 2 cross-quad shuffles; sum via MFMA
    float alph[2];
#pragma unroll
    for (int c = 0; c < 2; c++) {
      float mx = sf[c][0][0];
#pragma unroll
      for (int t = 0; t < 4; t++)
#pragma unroll
        for (int rr = 0; rr < 4; rr++) mx = fmaxf(mx, sf[c][t][rr]);
      mx = fmaxf(mx, __shfl_xor(mx, 16, 64));
      mx = fmaxf(mx, __shfl_xor(mx, 32, 64));
      float mnew = fmaxf(mrun[c], mx);
      alph[c] = __builtin_amdgcn_exp2f(mrun[c] - mnew);
      mrun[c] = mnew;
#pragma unroll
      for (int t = 0; t < 4; t++)
#pragma unroll
        for (int rr = 0; rr < 4; rr++)
          sf[c][t][rr] = __builtin_amdgcn_exp2f(sf[c][t][rr] - mnew);
    }
    // O/l rescale only when some running max moved (wave-uniform branch)
    if (__any((alph[0] < 1.f) || (alph[1] < 1.f))) {
#pragma unroll
      for (int g = 0; g < 2; g++)
#pragma unroll
        for (int rr = 0; rr < 4; rr++) {
          float ao = __shfl(alph[g], quad * 4 + rr, 64);
#pragma unroll
          for (int t = 0; t < 4; t++) Oa[g][t][rr] *= ao;
          lacc[g][rr] *= ao;
        }
    }
    // P -> LDS in A-layout [q][s], b64 packed (wave-local; DS in-order/wave)
#pragma unroll
    for (int c = 0; c < 2; c++) {
      int row = c * 16 + l15;
#pragma unroll
      for (int t = 0; t < 4; t++) {
        uint2 pkk;
        pkk.x = pk2bf(sf[c][t][0], sf[c][t][1]);
        pkk.y = pk2bf(sf[c][t][2], sf[c][t][3]);
        int chnk = 2 * t + (quad >> 1);
        *(uint2*)((char*)ps[w] + row * 128 + ((chnk ^ (row & 7)) * 16) + (quad & 1) * 8) = pkk;
      }
    }
    __builtin_amdgcn_wave_barrier();
    bf16x8 ap[2][2];
#pragma unroll
    for (int g = 0; g < 2; g++)
#pragma unroll
      for (int hh = 0; hh < 2; hh++)
        ap[g][hh] = *(const bf16x8*)swz(ps[w], g * 16 + l15, hh * 4 + quad);
    // O += P.V ; l += P.1 (ones-B MFMA, lands in (quad,r) domain)
#pragma unroll
    for (int t = 0; t < 4; t++) {
      bf16x8 bv0 = *(const bf16x8*)swz(vs, t * 16 + l15, quad);
      bf16x8 bv1 = *(const bf16x8*)swz(vs, t * 16 + l15, 4 + quad);
#pragma unroll
      for (int g = 0; g < 2; g++) {
        Oa[g][t] = mfma16(ap[g][0], bv0, Oa[g][t]);
        Oa[g][t] = mfma16(ap[g][1], bv1, Oa[g][t]);
      }
    }
#pragma unroll
    for (int g = 0; g < 2; g++) {
      lacc[g] = mfma16(ap[g][0], ones, lacc[g]);
      lacc[g] = mfma16(ap[g][1], ones, lacc[g]);
    }
    if (pf) {  // commit prefetched tile
      __syncthreads();  // all reads of ks/vs done
      *(uint4*)swz(ks, r0, c0) = pk0;
      *(uint4*)swz(ks, r1, c0) = pk1;
      *(uint4*)swz(vs, r0, c0) = pv0;
      *(uint4*)swz(vs, r1, c0) = pv1;
      __syncthreads();  // next tile staged
    }
  }

  // epilogue: O rows q=quad*4+r (C-layout), cols d=t*16+l15; l per-(quad,r)
#pragma unroll
  for (int g = 0; g < 2; g++)
#pragma unroll
    for (int rr = 0; rr < 4; rr++) {
      float inv = 1.f / lacc[g][rr];
      int qg = Q0 + w * 32 + g * 16 + quad * 4 + rr;
      size_t rowb = ((size_t)(bb * S_LEN + qg)) * NF + h * HD;
#pragma unroll
      for (int t = 0; t < 4; t++)
        ob[rowb + t * 16 + l15] = f2bf(Oa[g][t][rr] * inv);
    }
}

extern "C" void kernel_launch(void* const* d_in, const int* in_sizes, int n_in,
                              void* d_out, int out_size, void* d_ws, size_t ws_size,
                              hipStream_t stream) {
  const float* x  = (const float*)d_in[0];
  const int* pos  = (const int*)d_in[1];
  const float* Wq = (const float*)d_in[2];
  const float* bq = (const float*)d_in[3];
  const float* Wk = (const float*)d_in[4];
  const float* bk = (const float*)d_in[5];
  const float* Wv = (const float*)d_in[6];
  const float* bv = (const float*)d_in[7];
  const float* Wo = (const float*)d_in[8];
  const float* bo = (const float*)d_in[9];
  float* out = (float*)d_out;

  u16* xb  = (u16*)d_ws;                    // [M][F] bf16, reused later as attn out
  u16* wtq = xb + (size_t)M_TOT * NF;
  u16* wtk = wtq + (size_t)NF * NF;
  u16* wtv = wtk + (size_t)NF * NF;
  u16* wto = wtv + (size_t)NF * NF;
  u16* qb  = wto + (size_t)NF * NF;         // [bh][s][d] (pre-scaled by 0.125*log2e)
  u16* kb  = qb + (size_t)M_TOT * NF;       // [bh][s][d]
  u16* vtb = kb + (size_t)M_TOT * NF;       // [bh][d][s]
  float2* rtab = (float2*)(vtb + (size_t)M_TOT * NF);
  u16* attnb = xb;  // alias: xb no longer needed after QKV GEMM

  cast_kernel<<<dim3(M_TOT * NF / 1024), 256, 0, stream>>>(x, xb);
  rope_table_kernel<<<dim3(NB * S_LEN * 32 / 256), 256, 0, stream>>>(pos, rtab);
  wtrans_kernel<<<dim3(32, 32, 4), dim3(32, 8), 0, stream>>>(Wq, Wk, Wv, Wo,
                                                             wtq, wtk, wtv, wto);
  gemm_qkv_kernel<<<dim3(8, 32, 3), 256, 0, stream>>>(xb, wtq, wtk, wtv, bq, bk, bv,
                                                      rtab, qb, kb, vtb);
  attn_kernel<<<dim3(512), 256, 0, stream>>>(qb, kb, vtb, attnb);
  gemm_o_kernel<<<dim3(8, 32), 256, 0, stream>>>(attnb, wto, bo, out);
}

// Round 7
// 212.909 us; speedup vs baseline: 1.5342x; 1.5342x over previous
//
#include <hip/hip_runtime.h>
#include <hip/hip_bf16.h>

#define S_LEN 2048
#define NF 1024
#define NH 16
#define HD 64
#define NB 2
#define M_TOT 4096  // NB*S_LEN

typedef __bf16 bf16x8 __attribute__((ext_vector_type(8)));
typedef float f32x4 __attribute__((ext_vector_type(4)));
typedef unsigned short u16;

__device__ __forceinline__ u16 f2bf(float f) {
  union { float f; unsigned u; } v; v.f = f;
  unsigned r = v.u + 0x7FFFu + ((v.u >> 16) & 1u);
  return (u16)(r >> 16);
}

__device__ __forceinline__ unsigned pk2bf(float a, float b) {
  __hip_bfloat162 t = __float22bfloat162_rn(make_float2(a, b));
  union { __hip_bfloat162 h; unsigned u; } u; u.h = t; return u.u;
}

__device__ __forceinline__ f32x4 mfma16(bf16x8 a, bf16x8 b, f32x4 c) {
  return __builtin_amdgcn_mfma_f32_16x16x32_bf16(a, b, c, 0, 0, 0);
}

// async global->LDS 16B: lds dest is wave-uniform base + lane*16
__device__ __forceinline__ void gll16(const u16* g, u16* l) {
  __builtin_amdgcn_global_load_lds(
      (const __attribute__((address_space(1))) unsigned int*)g,
      (__attribute__((address_space(3))) unsigned int*)l, 16, 0, 0);
}

// XOR-swizzled LDS addressing: 64-u16 rows (128 B = 8 chunks of 16 B),
// chunk' = chunk ^ (row&7) -> conflict-free b128 for staging writes and
// fragment reads (verified: R3 dropped SQ_LDS_BANK_CONFLICT 5.4M->1.1M).
__device__ __forceinline__ u16* swz(u16* base, int row, int chunk) {
  return (u16*)((char*)base + row * 128 + ((chunk ^ (row & 7)) * 16));
}
__device__ __forceinline__ const u16* swz(const u16* base, int row, int chunk) {
  return (const u16*)((const char*)base + row * 128 + ((chunk ^ (row & 7)) * 16));
}

// ---- cast fp32 -> bf16, 4 elems/thread ----
__global__ void __launch_bounds__(256) cast_kernel(const float* __restrict__ in,
                                                   u16* __restrict__ out) {
  int i = (blockIdx.x * 256 + threadIdx.x) * 4;
  float4 v = *(const float4*)(in + i);
  ushort4 o;
  o.x = f2bf(v.x); o.y = f2bf(v.y); o.z = f2bf(v.z); o.w = f2bf(v.w);
  *(ushort4*)(out + i) = o;
}

// ---- rope table: tab[(b*S+s)*32 + p] = (sin, cos) ----
__global__ void __launch_bounds__(256) rope_table_kernel(const int* __restrict__ positions,
                                                         float2* __restrict__ tab) {
  int idx = blockIdx.x * 256 + threadIdx.x;  // < NB*S_LEN*32
  int p = idx & 31;
  int bs = idx >> 5;
  float pos = (float)positions[bs];
  float ang = pos / __powf(10000.0f, (float)p * (1.0f / 32.0f));
  float sn, cs;
  sincosf(ang, &sn, &cs);
  tab[idx] = make_float2(sn, cs);
}

// ---- weight transpose + cast (all 4 weights in one dispatch): Wt[n][k] = W[k][n] ----
__global__ void __launch_bounds__(256) wtrans_kernel(
    const float* __restrict__ W0, const float* __restrict__ W1,
    const float* __restrict__ W2, const float* __restrict__ W3,
    u16* __restrict__ T0, u16* __restrict__ T1,
    u16* __restrict__ T2, u16* __restrict__ T3) {
  const float* W = (blockIdx.z == 0) ? W0 : (blockIdx.z == 1) ? W1 : (blockIdx.z == 2) ? W2 : W3;
  u16* Wt = (blockIdx.z == 0) ? T0 : (blockIdx.z == 1) ? T1 : (blockIdx.z == 2) ? T2 : T3;
  __shared__ float t[32][33];
  int n0 = blockIdx.x * 32, k0 = blockIdx.y * 32;
  int tx = threadIdx.x, ty0 = threadIdx.y;
#pragma unroll
  for (int i = 0; i < 4; i++) {
    int ty = ty0 + i * 8;
    t[ty][tx] = W[(size_t)(k0 + ty) * NF + n0 + tx];
  }
  __syncthreads();
#pragma unroll
  for (int i = 0; i < 4; i++) {
    int ty = ty0 + i * 8;
    Wt[(size_t)(n0 + ty) * NF + k0 + tx] = f2bf(t[tx][ty]);
  }
}

// 128x128 tile bf16 GEMM core: C = A[M,K] * Bt[N,K]^T, K=1024.
// Unpadded [128][32] u16 tiles staged via global_load_lds (m97 pattern).
__device__ __forceinline__ void mm_core(const u16* __restrict__ A, const u16* __restrict__ Bt,
                                        int m0, int n0, u16* As, u16* Bs, f32x4 acc[4][4]) {
  const int tid = threadIdx.x;
  const int lane = tid & 63, w = tid >> 6;
  const int l15 = lane & 15, quad = lane >> 4;
  const int wr = w >> 1, wc = w & 1;
#pragma unroll
  for (int i = 0; i < 4; i++)
#pragma unroll
    for (int j = 0; j < 4; j++) {
      f32x4 z = {0.f, 0.f, 0.f, 0.f};
      acc[i][j] = z;
    }
  for (int k0 = 0; k0 < NF; k0 += 32) {
    __syncthreads();  // prior tile's reads done before overwrite
#pragma unroll
    for (int i = 0; i < 2; i++) {
      int ci = (w * 2 + i) * 64 + lane;  // chunk index in [0,512)
      int row = ci >> 2, c = ci & 3;
      gll16(&A[(size_t)(m0 + row) * NF + k0 + c * 8], &As[(w * 2 + i) * 512]);
      gll16(&Bt[(size_t)(n0 + row) * NF + k0 + c * 8], &Bs[(w * 2 + i) * 512]);
    }
    __syncthreads();  // drains vmcnt: tiles staged
    bf16x8 af[4], bfr[4];
#pragma unroll
    for (int i = 0; i < 4; i++)
      af[i] = *(const bf16x8*)&As[(wr * 64 + i * 16 + l15) * 32 + quad * 8];
#pragma unroll
    for (int j = 0; j < 4; j++)
      bfr[j] = *(const bf16x8*)&Bs[(wc * 64 + j * 16 + l15) * 32 + quad * 8];
#pragma unroll
    for (int i = 0; i < 4; i++)
#pragma unroll
      for (int j = 0; j < 4; j++)
        acc[i][j] = mfma16(af[i], bfr[j], acc[i][j]);
  }
}

#define QSCL 0.18033688f  // 0.125 * log2(e): folds score scale + exp->exp2 into q

// ---- fused QKV projection: z=0 -> q (rope, scaled), z=1 -> k (rope), z=2 -> v (transposed) ----
__global__ void __launch_bounds__(256) gemm_qkv_kernel(
    const u16* __restrict__ xb,
    const u16* __restrict__ wtq, const u16* __restrict__ wtk, const u16* __restrict__ wtv,
    const float* __restrict__ bq, const float* __restrict__ bk, const float* __restrict__ bv,
    const float2* __restrict__ rtab,
    u16* __restrict__ qo, u16* __restrict__ ko, u16* __restrict__ vto) {
  __shared__ u16 As[128 * 32], Bs[128 * 32];
  const int z = blockIdx.z;
  const u16* Wt = (z == 0) ? wtq : (z == 1) ? wtk : wtv;
  const float* bias = (z == 0) ? bq : (z == 1) ? bk : bv;
  const int m0 = blockIdx.y * 128, n0 = blockIdx.x * 128;
  f32x4 acc[4][4];
  mm_core(xb, Wt, m0, n0, As, Bs, acc);
  const int tid = threadIdx.x;
  const int lane = tid & 63, w = tid >> 6;
  const int l15 = lane & 15, quad = lane >> 4;
  const int wr = w >> 1, wc = w & 1;
  if (z < 2) {
    u16* out = (z == 0) ? qo : ko;
    const float oscl = (z == 0) ? QSCL : 1.0f;
#pragma unroll
    for (int i = 0; i < 4; i++) {
#pragma unroll
      for (int r = 0; r < 4; r++) {
        int gm = m0 + wr * 64 + i * 16 + quad * 4 + r;  // = b*S + s
        int b = gm >> 11, s = gm & 2047;
#pragma unroll
        for (int j = 0; j < 2; j++) {
          int col1 = n0 + wc * 64 + j * 16 + l15;
          int p = j * 16 + l15;
          float2 sc = rtab[gm * 32 + p];
          float x1 = acc[i][j][r] + bias[col1];
          float x2 = acc[i][j + 2][r] + bias[col1 + 32];
          float o1 = (x1 * sc.y - x2 * sc.x) * oscl;
          float o2 = (x2 * sc.y + x1 * sc.x) * oscl;
          int h = col1 >> 6;
          size_t base = ((size_t)((b * NH + h) * S_LEN + s)) * HD;
          out[base + p] = f2bf(o1);
          out[base + p + 32] = f2bf(o2);
        }
      }
    }
  } else {
    // v: write transposed [bh][d][s]
#pragma unroll
    for (int i = 0; i < 4; i++) {
      int gm0 = m0 + wr * 64 + i * 16 + quad * 4;
      int b = gm0 >> 11, s0 = gm0 & 2047;
#pragma unroll
      for (int j = 0; j < 4; j++) {
        int col = n0 + wc * 64 + j * 16 + l15;
        int h = col >> 6, d = col & 63;
        float bb = bias[col];
        ushort4 pk;
        pk.x = f2bf(acc[i][j][0] + bb);
        pk.y = f2bf(acc[i][j][1] + bb);
        pk.z = f2bf(acc[i][j][2] + bb);
        pk.w = f2bf(acc[i][j][3] + bb);
        *(ushort4*)&vto[((size_t)((b * NH + h) * HD + d)) * S_LEN + s0] = pk;
      }
    }
  }
}

// ---- output projection: fp32 out ----
__global__ void __launch_bounds__(256) gemm_o_kernel(const u16* __restrict__ ab,
                                                     const u16* __restrict__ wto,
                                                     const float* __restrict__ bo,
                                                     float* __restrict__ out) {
  __shared__ u16 As[128 * 32], Bs[128 * 32];
  const int m0 = blockIdx.y * 128, n0 = blockIdx.x * 128;
  f32x4 acc[4][4];
  mm_core(ab, wto, m0, n0, As, Bs, acc);
  const int tid = threadIdx.x;
  const int lane = tid & 63, w = tid >> 6;
  const int l15 = lane & 15, quad = lane >> 4;
  const int wr = w >> 1, wc = w & 1;
#pragma unroll
  for (int i = 0; i < 4; i++) {
#pragma unroll
    for (int j = 0; j < 4; j++) {
      int col = n0 + wc * 64 + j * 16 + l15;
      float bb = bo[col];
#pragma unroll
      for (int r = 0; r < 4; r++) {
        int gm = m0 + wr * 64 + i * 16 + quad * 4 + r;
        out[(size_t)gm * NF + col] = acc[i][j][r] + bb;
      }
    }
  }
}

// ---- flash attention, causal, S^T formulation, 64-row q-tiles ----
// 1024 blocks (bh, qt in 0..31): 64 q-rows/block, 16 q/wave. R3's proven
// per-iteration machinery (S^T, swizzle, b64 P-writes, ones-B MFMA row-sum,
// shuffle-free epilogue) in R2's high-parallelism shape: 24 KB LDS + ~90
// VGPR -> 4 blocks/CU (16 waves/CU) to overlap the per-iter serial chain.
// No launch_bounds cap beyond 256 (R5/R6 lesson: caps below ~112 -> spills).
__global__ void __launch_bounds__(256) attn_kernel(
    const u16* __restrict__ qb, const u16* __restrict__ kb,
    const u16* __restrict__ vtb, u16* __restrict__ ob) {
  __shared__ u16 ks[64 * 64];     // [s' (64)][d (64)] swizzled
  __shared__ u16 vs[64 * 64];     // [d (64)][s' (64)] swizzled
  __shared__ u16 ps[4][16 * 64];  // per-wave P relayout (2 KB each)
  const int bx = blockIdx.x;
  // heavy-first complementary mapping: bx<512 -> qt 31..16, else qt 0..15
  const int qt = (bx < 512) ? (31 - (bx >> 5)) : ((bx - 512) >> 5);
  const int bh = bx & 31;
  const int tid = threadIdx.x;
  const int lane = tid & 63, w = tid >> 6, l15 = lane & 15, quad = lane >> 4;
  const int bb = bh >> 4, h = bh & 15;
  const size_t kvbase = (size_t)bh * S_LEN;
  const size_t vbase = (size_t)bh * HD;
  const int Q0 = qt * 64;
  const int nit = qt + 1;
  const int r0 = tid >> 3, c0 = tid & 7;  // staging: 64 rows x 8 chunks
  const int r1 = r0 + 32;

  bf16x8 ones;
#pragma unroll
  for (int i = 0; i < 8; i++) ones[i] = (__bf16)1.0f;

  // Q fragment (B-operand: col=l15=q, k=quad*8+j=d); wave w owns q = Q0+w*16..+15
  bf16x8 qf[2];
  {
    const u16* qrow = &qb[(kvbase + Q0 + w * 16 + l15) * HD];
#pragma unroll
    for (int hh = 0; hh < 2; hh++)
      qf[hh] = *(const bf16x8*)&qrow[hh * 32 + quad * 8];
  }

  float mrun = -1e30f;
  f32x4 Oa[4], lacc;
  { f32x4 z = {0.f, 0.f, 0.f, 0.f}; lacc = z;
#pragma unroll
    for (int t = 0; t < 4; t++) Oa[t] = z; }

  // stage first K/V tile
  *(uint4*)swz(ks, r0, c0) = *(const uint4*)&kb[(kvbase + r0) * HD + c0 * 8];
  *(uint4*)swz(ks, r1, c0) = *(const uint4*)&kb[(kvbase + r1) * HD + c0 * 8];
  *(uint4*)swz(vs, r0, c0) = *(const uint4*)&vtb[(vbase + r0) * S_LEN + c0 * 8];
  *(uint4*)swz(vs, r1, c0) = *(const uint4*)&vtb[(vbase + r1) * S_LEN + c0 * 8];
  __syncthreads();

  for (int it = 0; it < nit; ++it) {
    const int k0 = it * 64;
    const bool pf = (it + 1 < nit);
    uint4 pk0, pk1, pv0, pv1;
    if (pf) {  // register prefetch of next K/V tile (overlaps compute)
      int k1 = k0 + 64;
      pk0 = *(const uint4*)&kb[(kvbase + k1 + r0) * HD + c0 * 8];
      pk1 = *(const uint4*)&kb[(kvbase + k1 + r1) * HD + c0 * 8];
      pv0 = *(const uint4*)&vtb[(vbase + r0) * S_LEN + k1 + c0 * 8];
      pv1 = *(const uint4*)&vtb[(vbase + r1) * S_LEN + k1 + c0 * 8];
    }
    // S^T = K.Q^T : 64s x 16q per wave
    f32x4 sf[4];
#pragma unroll
    for (int t = 0; t < 4; t++) {
      bf16x8 ak0 = *(const bf16x8*)swz(ks, t * 16 + l15, quad);
      bf16x8 ak1 = *(const bf16x8*)swz(ks, t * 16 + l15, 4 + quad);
      f32x4 z = {0.f, 0.f, 0.f, 0.f};
      z = mfma16(ak0, qf[0], z);
      z = mfma16(ak1, qf[1], z);
      sf[t] = z;
    }
    if (it == qt) {  // causal mask (diagonal tile only)
      int qg = Q0 + w * 16 + l15;
#pragma unroll
      for (int t = 0; t < 4; t++)
#pragma unroll
        for (int rr = 0; rr < 4; rr++)
          if (k0 + t * 16 + quad * 4 + rr > qg) sf[t][rr] = -1e30f;
    }
    // online softmax per q (lane-local column): in-lane max + 2 shuffles
    float alph;
    {
      float mx = sf[0][0];
#pragma unroll
      for (int t = 0; t < 4; t++)
#pragma unroll
        for (int rr = 0; rr < 4; rr++) mx = fmaxf(mx, sf[t][rr]);
      mx = fmaxf(mx, __shfl_xor(mx, 16, 64));
      mx = fmaxf(mx, __shfl_xor(mx, 32, 64));
      float mnew = fmaxf(mrun, mx);
      alph = __builtin_amdgcn_exp2f(mrun - mnew);
      mrun = mnew;
#pragma unroll
      for (int t = 0; t < 4; t++)
#pragma unroll
        for (int rr = 0; rr < 4; rr++)
          sf[t][rr] = __builtin_amdgcn_exp2f(sf[t][rr] - mnew);
    }
    // O/l rescale only when a running max moved (wave-uniform branch)
    if (__any(alph < 1.f)) {
#pragma unroll
      for (int rr = 0; rr < 4; rr++) {
        float ao = __shfl(alph, quad * 4 + rr, 64);
#pragma unroll
        for (int t = 0; t < 4; t++) Oa[t][rr] *= ao;
        lacc[rr] *= ao;
      }
    }
    // P -> LDS in A-layout [q][s], b64 packed (wave-local; DS in-order/wave)
#pragma unroll
    for (int t = 0; t < 4; t++) {
      uint2 pkk;
      pkk.x = pk2bf(sf[t][0], sf[t][1]);
      pkk.y = pk2bf(sf[t][2], sf[t][3]);
      int chnk = 2 * t + (quad >> 1);
      *(uint2*)((char*)ps[w] + l15 * 128 + ((chnk ^ (l15 & 7)) * 16) + (quad & 1) * 8) = pkk;
    }
    __builtin_amdgcn_wave_barrier();
    bf16x8 ap[2];
#pragma unroll
    for (int hh = 0; hh < 2; hh++)
      ap[hh] = *(const bf16x8*)swz(ps[w], l15, hh * 4 + quad);
    // O += P.V ; l += P.1 (ones-B MFMA, lands in (quad,r) domain)
#pragma unroll
    for (int t = 0; t < 4; t++) {
      bf16x8 bv0 = *(const bf16x8*)swz(vs, t * 16 + l15, quad);
      bf16x8 bv1 = *(const bf16x8*)swz(vs, t * 16 + l15, 4 + quad);
      Oa[t] = mfma16(ap[0], bv0, Oa[t]);
      Oa[t] = mfma16(ap[1], bv1, Oa[t]);
    }
    lacc = mfma16(ap[0], ones, lacc);
    lacc = mfma16(ap[1], ones, lacc);
    if (pf) {  // commit prefetched tile
      __syncthreads();  // all reads of ks/vs done
      *(uint4*)swz(ks, r0, c0) = pk0;
      *(uint4*)swz(ks, r1, c0) = pk1;
      *(uint4*)swz(vs, r0, c0) = pv0;
      *(uint4*)swz(vs, r1, c0) = pv1;
      __syncthreads();  // next tile staged
    }
  }

  // epilogue: O rows q=quad*4+rr (C-layout), cols d=t*16+l15; l per-(quad,rr)
#pragma unroll
  for (int rr = 0; rr < 4; rr++) {
    float inv = 1.f / lacc[rr];
    int qg = Q0 + w * 16 + quad * 4 + rr;
    size_t rowb = ((size_t)(bb * S_LEN + qg)) * NF + h * HD;
#pragma unroll
    for (int t = 0; t < 4; t++)
      ob[rowb + t * 16 + l15] = f2bf(Oa[t][rr] * inv);
  }
}

extern "C" void kernel_launch(void* const* d_in, const int* in_sizes, int n_in,
                              void* d_out, int out_size, void* d_ws, size_t ws_size,
                              hipStream_t stream) {
  const float* x  = (const float*)d_in[0];
  const int* pos  = (const int*)d_in[1];
  const float* Wq = (const float*)d_in[2];
  const float* bq = (const float*)d_in[3];
  const float* Wk = (const float*)d_in[4];
  const float* bk = (const float*)d_in[5];
  const float* Wv = (const float*)d_in[6];
  const float* bv = (const float*)d_in[7];
  const float* Wo = (const float*)d_in[8];
  const float* bo = (const float*)d_in[9];
  float* out = (float*)d_out;

  u16* xb  = (u16*)d_ws;                    // [M][F] bf16, reused later as attn out
  u16* wtq = xb + (size_t)M_TOT * NF;
  u16* wtk = wtq + (size_t)NF * NF;
  u16* wtv = wtk + (size_t)NF * NF;
  u16* wto = wtv + (size_t)NF * NF;
  u16* qb  = wto + (size_t)NF * NF;         // [bh][s][d] (pre-scaled by 0.125*log2e)
  u16* kb  = qb + (size_t)M_TOT * NF;       // [bh][s][d]
  u16* vtb = kb + (size_t)M_TOT * NF;       // [bh][d][s]
  float2* rtab = (float2*)(vtb + (size_t)M_TOT * NF);
  u16* attnb = xb;  // alias: xb no longer needed after QKV GEMM

  cast_kernel<<<dim3(M_TOT * NF / 1024), 256, 0, stream>>>(x, xb);
  rope_table_kernel<<<dim3(NB * S_LEN * 32 / 256), 256, 0, stream>>>(pos, rtab);
  wtrans_kernel<<<dim3(32, 32, 4), dim3(32, 8), 0, stream>>>(Wq, Wk, Wv, Wo,
                                                             wtq, wtk, wtv, wto);
  gemm_qkv_kernel<<<dim3(8, 32, 3), 256, 0, stream>>>(xb, wtq, wtk, wtv, bq, bk, bv,
                                                      rtab, qb, kb, vtb);
  attn_kernel<<<dim3(1024), 256, 0, stream>>>(qb, kb, vtb, attnb);
  gemm_o_kernel<<<dim3(8, 32), 256, 0, stream>>>(attnb, wto, bo, out);
}